// Round 1
// baseline (1337.177 us; speedup 1.0000x reference)
//
#include <hip/hip_runtime.h>

// TinyLSTM: I=128, H=64, C=10, B=256, T=1024
// Round 1: fused fp32 baseline. One block per batch element (256 blocks = 256 CUs),
// 256 threads (thread = gate). Weights held in VGPRs (192 floats/thread,
// __launch_bounds__(256,1) -> 1 wave/SIMD, ~500 VGPR budget, no spill).
// x row staged via LDS with depth-2 register prefetch; custom lgkmcnt-only
// barrier keeps the global prefetch in flight across the per-step syncs.

#define NI 128   // input size
#define NH 64    // hidden size
#define NG 256   // 4*NH gates
#define NB 256   // batch
#define NT 1024  // seq len
#define NC 10    // classes

__device__ __forceinline__ void block_sync_lds() {
    // barrier that drains LDS (lgkmcnt) but NOT vmcnt: keeps the global x-row
    // prefetch in flight across the per-step sync. Compiler still inserts
    // vmcnt waits before any *use* of prefetched registers.
    asm volatile("s_waitcnt lgkmcnt(0)\n\ts_barrier" ::: "memory");
}

__device__ __forceinline__ float fast_sigmoid(float x) {
    x = fminf(fmaxf(x, -30.f), 30.f);
    return 1.f / (1.f + __expf(-x));
}

__device__ __forceinline__ float fast_tanh(float x) {
    x = fminf(fmaxf(x, -15.f), 15.f);   // tanh saturates ~1 by |x|=9; avoids exp overflow
    float e = __expf(2.f * x);
    return (e - 1.f) / (e + 1.f);
}

__global__ __launch_bounds__(NG, 1)
void lstm_fused_kernel(const float* __restrict__ x,
                       const float* __restrict__ W_ih,
                       const float* __restrict__ W_hh,
                       const float* __restrict__ b_ih,
                       const float* __restrict__ b_hh,
                       const float* __restrict__ W_cls,
                       const float* __restrict__ b_cls,
                       float* __restrict__ out) {
    const int b = blockIdx.x;
    const int g = threadIdx.x;   // gate index 0..255; PyTorch order [i,f,g,o] blocks of NH

    __shared__ float xs[NI];     // current x row (broadcast-read by all waves)
    __shared__ float hs[NH];     // hidden state
    __shared__ float acts[NG];   // post-activation gates

    // ---- load this gate's weight rows into registers (one-time) ----
    float4 wih[NI / 4];   // 128 floats
    float4 whh[NH / 4];   // 64 floats
    {
        const float4* p = (const float4*)(W_ih + (size_t)g * NI);
        #pragma unroll
        for (int k = 0; k < NI / 4; ++k) wih[k] = p[k];
        const float4* q = (const float4*)(W_hh + (size_t)g * NH);
        #pragma unroll
        for (int k = 0; k < NH / 4; ++k) whh[k] = q[k];
    }
    const float bias = b_ih[g] + b_hh[g];

    const float* xrow = x + (size_t)b * NT * NI;

    // stage x[t=0], prefetch x[t=1]
    float4 xpre = make_float4(0.f, 0.f, 0.f, 0.f);
    if (g < NI / 4) {
        ((float4*)xs)[g] = ((const float4*)xrow)[g];
        xpre = ((const float4*)(xrow + NI))[g];
    }
    if (g < NH) hs[g] = 0.f;
    float c = 0.f;   // cell state, lives in lane g of wave 0 (g < NH)

    for (int t = 0; t < NT; ++t) {
        block_sync_lds();   // xs/hs writes from previous iteration visible

        // gates[g] = bias + W_ih[g,:].x_t + W_hh[g,:].h_t
        float a0 = bias, a1 = 0.f, a2 = 0.f, a3 = 0.f;
        const float4* xs4 = (const float4*)xs;
        #pragma unroll
        for (int k = 0; k < NI / 4; ++k) {
            float4 xv = xs4[k];
            a0 = fmaf(wih[k].x, xv.x, a0);
            a1 = fmaf(wih[k].y, xv.y, a1);
            a2 = fmaf(wih[k].z, xv.z, a2);
            a3 = fmaf(wih[k].w, xv.w, a3);
        }
        const float4* hs4 = (const float4*)hs;
        #pragma unroll
        for (int k = 0; k < NH / 4; ++k) {
            float4 hv = hs4[k];
            a0 = fmaf(whh[k].x, hv.x, a0);
            a1 = fmaf(whh[k].y, hv.y, a1);
            a2 = fmaf(whh[k].z, hv.z, a2);
            a3 = fmaf(whh[k].w, hv.w, a3);
        }
        float pre = (a0 + a1) + (a2 + a3);

        // block [2H,3H) is g-gate -> tanh, rest sigmoid. Branch is wave-uniform
        // (wave 2 exactly covers [128,192)).
        float av;
        if (g >= 2 * NH && g < 3 * NH) av = fast_tanh(pre);
        else                           av = fast_sigmoid(pre);
        acts[g] = av;

        block_sync_lds();   // acts complete

        if (g < NH) {       // wave 0: state update
            float i_t = acts[g];
            float f_t = acts[NH + g];
            float g_t = acts[2 * NH + g];
            float o_t = acts[3 * NH + g];
            c = fmaf(f_t, c, i_t * g_t);
            hs[g] = o_t * fast_tanh(c);
        }
        if (g < NI / 4) {   // stage next x row, prefetch the one after
            if (t + 1 < NT) ((float4*)xs)[g] = xpre;
            if (t + 2 < NT) xpre = ((const float4*)(xrow + (size_t)(t + 2) * NI))[g];
        }
    }

    block_sync_lds();
    // epilogue: logits[b] = W_cls @ h_T + b_cls  (10 outputs, trivial)
    if (g < NC) {
        float acc = b_cls[g];
        const float* wc = W_cls + g * NH;
        #pragma unroll 8
        for (int k = 0; k < NH; ++k) acc = fmaf(wc[k], hs[k], acc);
        out[b * NC + g] = acc;
    }
}

extern "C" void kernel_launch(void* const* d_in, const int* in_sizes, int n_in,
                              void* d_out, int out_size, void* d_ws, size_t ws_size,
                              hipStream_t stream) {
    const float* x     = (const float*)d_in[0];
    const float* W_ih  = (const float*)d_in[1];
    const float* W_hh  = (const float*)d_in[2];
    const float* b_ih  = (const float*)d_in[3];
    const float* b_hh  = (const float*)d_in[4];
    const float* W_cls = (const float*)d_in[5];
    const float* b_cls = (const float*)d_in[6];
    float* out = (float*)d_out;

    lstm_fused_kernel<<<NB, NG, 0, stream>>>(x, W_ih, W_hh, b_ih, b_hh,
                                             W_cls, b_cls, out);
}

// Round 3
// 907.416 us; speedup vs baseline: 1.4736x; 1.4736x over previous
//
#include <hip/hip_runtime.h>

// TinyLSTM: I=128, H=64, C=10, B=256, T=1024
// Round 3: = Round 2 (packed-f16 broadcast + v_dot2_f32_f16) with the
// half2 typedef fixed to __fp16-based vector (what cvt_pkrtz/fdot2 expect).
// R1 post-mortem: LDS return BW was the wall (192 KB/step float4 broadcast
// ~1536 cyc/step) and fp32 weights didn't fit in VGPRs (VGPR_Count=112).
// Fix: z=[x;h] packed f16 in LDS (24 KB/step broadcast), weights packed to
// f16 pairs in VGPRs (96 dwords), dot via v_dot2_f32_f16, fp32 accumulate.

#define NI 128   // input size
#define NH 64    // hidden size
#define NG 256   // 4*NH gates
#define NB 256   // batch
#define NT 1024  // seq len
#define NC 10    // classes

typedef __fp16 half2v __attribute__((ext_vector_type(2)));

__device__ __forceinline__ void block_sync_lds() {
    // barrier draining LDS (lgkmcnt) but NOT vmcnt: keeps the global x-row
    // prefetch in flight across per-step syncs.
    asm volatile("s_waitcnt lgkmcnt(0)\n\ts_barrier" ::: "memory");
}

__device__ __forceinline__ float fast_sigmoid(float x) {
    x = fminf(fmaxf(x, -30.f), 30.f);
    return 1.f / (1.f + __expf(-x));
}

__device__ __forceinline__ float fast_tanh(float x) {
    x = fminf(fmaxf(x, -15.f), 15.f);
    float e = __expf(2.f * x);
    return (e - 1.f) / (e + 1.f);
}

__device__ __forceinline__ unsigned pack2(float a, float b) {
    half2v h = __builtin_amdgcn_cvt_pkrtz(a, b);   // v_cvt_pkrtz_f16_f32
    return __builtin_bit_cast(unsigned, h);
}

__device__ __forceinline__ float dot2(unsigned w, unsigned z, float acc) {
#if __has_builtin(__builtin_amdgcn_fdot2)
    return __builtin_amdgcn_fdot2(__builtin_bit_cast(half2v, w),
                                  __builtin_bit_cast(half2v, z), acc, false);
#else
    half2v a = __builtin_bit_cast(half2v, w);
    half2v b = __builtin_bit_cast(half2v, z);
    return acc + (float)a[0] * (float)b[0] + (float)a[1] * (float)b[1];
#endif
}

__global__ __launch_bounds__(NG, 1)
void lstm_fused_f16_kernel(const float* __restrict__ x,
                           const float* __restrict__ W_ih,
                           const float* __restrict__ W_hh,
                           const float* __restrict__ b_ih,
                           const float* __restrict__ b_hh,
                           const float* __restrict__ W_cls,
                           const float* __restrict__ b_cls,
                           float* __restrict__ out) {
    const int b = blockIdx.x;
    const int g = threadIdx.x;   // gate index; PyTorch order [i,f,g,o], blocks of NH

    // z = [x_t (64 packed dwords) ; h_t (32 packed dwords)]
    __shared__ __align__(16) unsigned zs[NI / 2 + NH / 2];   // 96 dwords
    __shared__ float acts[NG];

    // ---- one-time: pack this gate's weight rows into f16-pair registers ----
    unsigned wp[96];   // 64 for W_ih, 32 for W_hh
    {
        const float2* p = (const float2*)(W_ih + (size_t)g * NI);
        #pragma unroll
        for (int j = 0; j < NI / 2; ++j) { float2 v = p[j]; wp[j] = pack2(v.x, v.y); }
        const float2* q = (const float2*)(W_hh + (size_t)g * NH);
        #pragma unroll
        for (int j = 0; j < NH / 2; ++j) { float2 v = q[j]; wp[NI / 2 + j] = pack2(v.x, v.y); }
    }
    const float bias = b_ih[g] + b_hh[g];

    const float* xrow = x + (size_t)b * NT * NI;
    const int lane1 = g - 64;    // wave 1 handles x staging

    // stage x[0] packed, prefetch x[1]; init packed h = 0
    float2 xpre = make_float2(0.f, 0.f);
    if (g >= 64 && g < 128) {
        float2 v = ((const float2*)xrow)[lane1];
        zs[lane1] = pack2(v.x, v.y);
        xpre = ((const float2*)(xrow + NI))[lane1];
    }
    if (g < NH / 2) zs[NI / 2 + g] = 0u;
    float c = 0.f;   // cell state in lane g (<NH) of wave 0

    const uint4* zs4 = (const uint4*)zs;

    for (int t = 0; t < NT; ++t) {
        block_sync_lds();   // zs writes for step t visible

        // pre-act[g] = bias + sum_k W[g,k] * z[k]  via packed dot2,
        // 4 independent accumulators (one per dword of each uint4).
        float a0 = bias, a1 = 0.f, a2 = 0.f, a3 = 0.f;
        #pragma unroll
        for (int k = 0; k < 24; ++k) {
            uint4 zv = zs4[k];
            a0 = dot2(wp[4 * k + 0], zv.x, a0);
            a1 = dot2(wp[4 * k + 1], zv.y, a1);
            a2 = dot2(wp[4 * k + 2], zv.z, a2);
            a3 = dot2(wp[4 * k + 3], zv.w, a3);
        }
        float pre = (a0 + a1) + (a2 + a3);

        // wave 2 exactly covers the g-gate block [128,192) -> uniform branch
        float av = (g >= 2 * NH && g < 3 * NH) ? fast_tanh(pre) : fast_sigmoid(pre);
        acts[g] = av;

        block_sync_lds();   // acts ready; all zs reads for step t complete

        if (g < NH) {
            // wave 0: state update + pack h into zs
            float i_t = acts[g];
            float f_t = acts[NH + g];
            float g_t = acts[2 * NH + g];
            float o_t = acts[3 * NH + g];
            c = fmaf(f_t, c, i_t * g_t);
            float hv = o_t * fast_tanh(c);
            float hn = __shfl_down(hv, 1);          // neighbor's h for packing
            if ((g & 1) == 0) zs[NI / 2 + (g >> 1)] = pack2(hv, hn);
        } else if (g < 128) {
            // wave 1: stage next x row packed, prefetch the one after
            if (t + 1 < NT) zs[lane1] = pack2(xpre.x, xpre.y);
            if (t + 2 < NT) xpre = ((const float2*)(xrow + (size_t)(t + 2) * NI))[lane1];
        }
    }

    block_sync_lds();
    // epilogue: logits[b] = W_cls @ h_T + b_cls (h_T read back from packed zs)
    if (g < NC) {
        float acc = b_cls[g];
        const float* wc = W_cls + g * NH;
        #pragma unroll
        for (int j = 0; j < NH / 2; ++j) {
            half2v hp = __builtin_bit_cast(half2v, zs[NI / 2 + j]);
            acc = fmaf(wc[2 * j],     (float)hp[0], acc);
            acc = fmaf(wc[2 * j + 1], (float)hp[1], acc);
        }
        out[b * NC + g] = acc;
    }
}

extern "C" void kernel_launch(void* const* d_in, const int* in_sizes, int n_in,
                              void* d_out, int out_size, void* d_ws, size_t ws_size,
                              hipStream_t stream) {
    const float* x     = (const float*)d_in[0];
    const float* W_ih  = (const float*)d_in[1];
    const float* W_hh  = (const float*)d_in[2];
    const float* b_ih  = (const float*)d_in[3];
    const float* b_hh  = (const float*)d_in[4];
    const float* W_cls = (const float*)d_in[5];
    const float* b_cls = (const float*)d_in[6];
    float* out = (float*)d_out;

    lstm_fused_f16_kernel<<<NB, NG, 0, stream>>>(x, W_ih, W_hh, b_ih, b_hh,
                                                 W_cls, b_cls, out);
}

// Round 4
// 789.487 us; speedup vs baseline: 1.6937x; 1.1494x over previous
//
#include <hip/hip_runtime.h>

// TinyLSTM: I=128, H=64, C=10, B=256, T=1024
// Round 4: phase-split.
//   Phase 1: x_proj = x @ W_ih^T via MFMA f16 GEMM (M=B*T=262144, N=256, K=128),
//            output packed f16 pairs (gate g, g+128) per dword into d_ws.
//   Phase 2: recurrence only. 256 blocks x 64 threads (ONE wave). Thread j owns
//            hidden unit j (gates j, 64+j, 128+j, 192+j) -> c/h update is
//            thread-local, zero barriers. h broadcast = 8 ds_read_b128/step.
//            W_hh rows in VGPRs (128 packed dwords) via waves_per_eu(1,1).
// R3 post-mortem: z-broadcast is an invariant LDS-delivery wall (98 KB/step/CU)
// and VGPR_Count=116 proved weights were never register-resident.

#define NI 128
#define NH 64
#define NG 256
#define NB 256
#define NT 1024
#define NC 10

typedef __fp16 half2v __attribute__((ext_vector_type(2)));
typedef __fp16 f16x8  __attribute__((ext_vector_type(8)));
typedef float  f32x4  __attribute__((ext_vector_type(4)));

__device__ __forceinline__ float fast_sigmoid(float x) {
    x = fminf(fmaxf(x, -30.f), 30.f);
    return 1.f / (1.f + __expf(-x));
}
__device__ __forceinline__ float fast_tanh(float x) {
    x = fminf(fmaxf(x, -15.f), 15.f);
    float e = __expf(2.f * x);
    return (e - 1.f) / (e + 1.f);
}
__device__ __forceinline__ unsigned pack2(float a, float b) {
    half2v h = __builtin_amdgcn_cvt_pkrtz(a, b);
    return __builtin_bit_cast(unsigned, h);
}
__device__ __forceinline__ float dot2(unsigned w, unsigned z, float acc) {
    return __builtin_amdgcn_fdot2(__builtin_bit_cast(half2v, w),
                                  __builtin_bit_cast(half2v, z), acc, false);
}

// ---------------------------------------------------------------- phase 1 ----
// Grid: 4096 blocks x 256 thr. Block handles 64 rows of x (row = b*T+t).
// Wave w: rows [bid*64 + w*16, +16), all 256 gates via 16 n-tiles, K=128 in 4 steps.
// W_ih staged in LDS as f16, XOR-swizzled 16B chunks (row r, chunk c stored at
// c ^ (r&15)) -> b-frag reads are 2-way-conflict max (free), 64 KB exactly.
__global__ __launch_bounds__(256)
void lstm_xproj_kernel(const float* __restrict__ x,
                       const float* __restrict__ W_ih,
                       unsigned* __restrict__ xp) {
    __shared__ __align__(16) unsigned short Wlds[NG * NI];   // 65536 B

    const int tid = threadIdx.x;
    // ---- stage W_ih (256x128 fp32) -> LDS f16, swizzled ----
    const float4* W4 = (const float4*)W_ih;
    #pragma unroll
    for (int it = 0; it < 32; ++it) {
        int e4 = it * 256 + tid;           // float4 index; 32 per gate row
        float4 w = W4[e4];
        int r = e4 >> 5;                   // gate row
        int q = e4 & 31;                   // float4 within row
        int c = q >> 1;                    // 16B chunk (8 f16)
        int half = q & 1;
        int cs = c ^ (r & 15);
        uint2 pw = make_uint2(pack2(w.x, w.y), pack2(w.z, w.w));
        *(uint2*)((char*)Wlds + (size_t)r * 256 + cs * 16 + half * 8) = pw;
    }
    __syncthreads();

    const int wv   = tid >> 6;             // wave 0..3
    const int lane = tid & 63;
    const int col  = lane & 15;
    const int quad = lane >> 4;
    const int m0   = blockIdx.x * 64 + wv * 16;

    // prefetch this wave's A rows: row m0+col, 8 floats per k-step
    const float* xr = x + (size_t)(m0 + col) * NI + quad * 8;
    float4 av[8];
    #pragma unroll
    for (int s = 0; s < 4; ++s) {
        av[2 * s]     = *(const float4*)(xr + s * 32);
        av[2 * s + 1] = *(const float4*)(xr + s * 32 + 4);
    }

    f32x4 acc[16];
    #pragma unroll
    for (int nt = 0; nt < 16; ++nt) acc[nt] = (f32x4){0.f, 0.f, 0.f, 0.f};

    #pragma unroll
    for (int s = 0; s < 4; ++s) {
        f16x8 afr;
        {
            half2v p0 = __builtin_amdgcn_cvt_pkrtz(av[2*s].x,   av[2*s].y);
            half2v p1 = __builtin_amdgcn_cvt_pkrtz(av[2*s].z,   av[2*s].w);
            half2v p2 = __builtin_amdgcn_cvt_pkrtz(av[2*s+1].x, av[2*s+1].y);
            half2v p3 = __builtin_amdgcn_cvt_pkrtz(av[2*s+1].z, av[2*s+1].w);
            afr[0]=p0[0]; afr[1]=p0[1]; afr[2]=p1[0]; afr[3]=p1[1];
            afr[4]=p2[0]; afr[5]=p2[1]; afr[6]=p3[0]; afr[7]=p3[1];
        }
        #pragma unroll
        for (int nt = 0; nt < 16; ++nt) {
            int n = nt * 16 + col;
            int chunk = s * 4 + quad;
            int cs = chunk ^ (n & 15);
            f16x8 bfr = *(const f16x8*)((char*)Wlds + (size_t)n * 256 + cs * 16);
            acc[nt] = __builtin_amdgcn_mfma_f32_16x16x32_f16(afr, bfr, acc[nt], 0, 0, 0);
        }
    }

    // epilogue: dword d = nt*16+col packs (gate d, gate d+128); row = m0+quad*4+r
    #pragma unroll
    for (int r = 0; r < 4; ++r) {
        int row = m0 + quad * 4 + r;
        #pragma unroll
        for (int nt = 0; nt < 8; ++nt) {
            unsigned v = pack2(acc[nt][r], acc[nt + 8][r]);
            xp[(size_t)row * 128 + nt * 16 + col] = v;
        }
    }
}

// ---------------------------------------------------------------- phase 2 ----
// 256 blocks x 64 threads. Thread j owns hidden unit j; gates i=j, f=64+j,
// g=128+j, o=192+j. W_hh rows packed f16 in VGPRs. h packed f16 in LDS (32 dw).
__global__ __attribute__((amdgpu_flat_work_group_size(64, 64), amdgpu_waves_per_eu(1, 1)))
void lstm_rec_kernel(const unsigned* __restrict__ xp,
                     const float* __restrict__ W_hh,
                     const float* __restrict__ b_ih,
                     const float* __restrict__ b_hh,
                     const float* __restrict__ W_cls,
                     const float* __restrict__ b_cls,
                     float* __restrict__ out) {
    const int b = blockIdx.x;
    const int j = threadIdx.x;

    __shared__ __align__(16) unsigned hz[NH / 2];   // h packed f16
    __shared__ float hf[NH];                        // final h fp32 for epilogue

    // ---- pack W_hh rows for this unit's four gates into registers ----
    uint4 w0[8], w1[8], w2[8], w3[8];
    {
        const float4* r0 = (const float4*)(W_hh + (size_t)(0 * NH + j) * NH);
        const float4* r1 = (const float4*)(W_hh + (size_t)(1 * NH + j + NH - NH + 64 - 64) * NH) + 0; // placeholder
    }
    {
        const float4* ri = (const float4*)(W_hh + (size_t)(j) * NH);
        const float4* rf = (const float4*)(W_hh + (size_t)(64 + j) * NH);
        const float4* rg = (const float4*)(W_hh + (size_t)(128 + j) * NH);
        const float4* ro = (const float4*)(W_hh + (size_t)(192 + j) * NH);
        #pragma unroll
        for (int k = 0; k < 8; ++k) {
            float4 a = ri[2*k], c4 = ri[2*k+1];
            w0[k] = make_uint4(pack2(a.x,a.y), pack2(a.z,a.w), pack2(c4.x,c4.y), pack2(c4.z,c4.w));
            a = rf[2*k]; c4 = rf[2*k+1];
            w1[k] = make_uint4(pack2(a.x,a.y), pack2(a.z,a.w), pack2(c4.x,c4.y), pack2(c4.z,c4.w));
            a = rg[2*k]; c4 = rg[2*k+1];
            w2[k] = make_uint4(pack2(a.x,a.y), pack2(a.z,a.w), pack2(c4.x,c4.y), pack2(c4.z,c4.w));
            a = ro[2*k]; c4 = ro[2*k+1];
            w3[k] = make_uint4(pack2(a.x,a.y), pack2(a.z,a.w), pack2(c4.x,c4.y), pack2(c4.z,c4.w));
        }
    }
    // pin packed weights into VGPRs
    #pragma unroll
    for (int k = 0; k < 8; ++k) {
        asm volatile("" : "+v"(w0[k].x), "+v"(w0[k].y), "+v"(w0[k].z), "+v"(w0[k].w));
        asm volatile("" : "+v"(w1[k].x), "+v"(w1[k].y), "+v"(w1[k].z), "+v"(w1[k].w));
        asm volatile("" : "+v"(w2[k].x), "+v"(w2[k].y), "+v"(w2[k].z), "+v"(w2[k].w));
        asm volatile("" : "+v"(w3[k].x), "+v"(w3[k].y), "+v"(w3[k].z), "+v"(w3[k].w));
    }

    const float bias_i = b_ih[j]       + b_hh[j];
    const float bias_f = b_ih[64 + j]  + b_hh[64 + j];
    const float bias_g = b_ih[128 + j] + b_hh[128 + j];
    const float bias_o = b_ih[192 + j] + b_hh[192 + j];

    if (j < NH / 2) hz[j] = 0u;
    asm volatile("s_waitcnt lgkmcnt(0)" ::: "memory");

    const unsigned* xpb = xp + (size_t)b * NT * 128;
    uint2 pf[4];
    #pragma unroll
    for (int s = 0; s < 4; ++s)
        pf[s] = make_uint2(xpb[(size_t)s * 128 + j], xpb[(size_t)s * 128 + 64 + j]);

    float c = 0.f, h = 0.f;
    const uint4* hz4 = (const uint4*)hz;

    for (int tb = 0; tb < NT; tb += 4) {
        #pragma unroll
        for (int s = 0; s < 4; ++s) {
            uint2 cur = pf[s];
            if (tb + 4 + s < NT) {
                const unsigned* row = xpb + (size_t)(tb + 4 + s) * 128;
                pf[s] = make_uint2(row[j], row[64 + j]);
            }
            // h-dot: 32 dot2 per gate, 2 accumulators each
            float ai = 0.f, bi = 0.f, af = 0.f, bf2 = 0.f;
            float ag = 0.f, bg = 0.f, ao = 0.f, bo = 0.f;
            #pragma unroll
            for (int k = 0; k < 8; ++k) {
                uint4 hh = hz4[k];
                ai  = dot2(w0[k].x, hh.x, ai);  ai  = dot2(w0[k].y, hh.y, ai);
                bi  = dot2(w0[k].z, hh.z, bi);  bi  = dot2(w0[k].w, hh.w, bi);
                af  = dot2(w1[k].x, hh.x, af);  af  = dot2(w1[k].y, hh.y, af);
                bf2 = dot2(w1[k].z, hh.z, bf2); bf2 = dot2(w1[k].w, hh.w, bf2);
                ag  = dot2(w2[k].x, hh.x, ag);  ag  = dot2(w2[k].y, hh.y, ag);
                bg  = dot2(w2[k].z, hh.z, bg);  bg  = dot2(w2[k].w, hh.w, bg);
                ao  = dot2(w3[k].x, hh.x, ao);  ao  = dot2(w3[k].y, hh.y, ao);
                bo  = dot2(w3[k].z, hh.z, bo);  bo  = dot2(w3[k].w, hh.w, bo);
            }
            half2v xig = __builtin_bit_cast(half2v, cur.x);   // (i, g) x-proj
            half2v xfo = __builtin_bit_cast(half2v, cur.y);   // (f, o) x-proj
            float i_t = fast_sigmoid(bias_i + (float)xig[0] + ai + bi);
            float f_t = fast_sigmoid(bias_f + (float)xfo[0] + af + bf2);
            float g_t = fast_tanh   (bias_g + (float)xig[1] + ag + bg);
            float o_t = fast_sigmoid(bias_o + (float)xfo[1] + ao + bo);
            c = fmaf(f_t, c, i_t * g_t);
            h = o_t * fast_tanh(c);
            // publish h (packed pairs) for next step
            float hn = __shfl_down(h, 1);
            if ((j & 1) == 0) hz[j >> 1] = pack2(h, hn);
            asm volatile("s_waitcnt lgkmcnt(0)" ::: "memory");
        }
    }

    hf[j] = h;
    asm volatile("s_waitcnt lgkmcnt(0)" ::: "memory");
    if (j < NC) {
        float acc = b_cls[j];
        const float* wc = W_cls + j * NH;
        #pragma unroll 8
        for (int k = 0; k < NH; ++k) acc = fmaf(wc[k], hf[k], acc);
        out[b * NC + j] = acc;
    }
}

// ------------------------------------------------------------- fallback (R3) --
__device__ __forceinline__ void block_sync_lds() {
    asm volatile("s_waitcnt lgkmcnt(0)\n\ts_barrier" ::: "memory");
}

__global__ __launch_bounds__(NG, 1)
void lstm_fused_f16_kernel(const float* __restrict__ x,
                           const float* __restrict__ W_ih,
                           const float* __restrict__ W_hh,
                           const float* __restrict__ b_ih,
                           const float* __restrict__ b_hh,
                           const float* __restrict__ W_cls,
                           const float* __restrict__ b_cls,
                           float* __restrict__ out) {
    const int b = blockIdx.x;
    const int g = threadIdx.x;
    __shared__ __align__(16) unsigned zs[NI / 2 + NH / 2];
    __shared__ float acts[NG];
    unsigned wp[96];
    {
        const float2* p = (const float2*)(W_ih + (size_t)g * NI);
        #pragma unroll
        for (int jj = 0; jj < NI / 2; ++jj) { float2 v = p[jj]; wp[jj] = pack2(v.x, v.y); }
        const float2* q = (const float2*)(W_hh + (size_t)g * NH);
        #pragma unroll
        for (int jj = 0; jj < NH / 2; ++jj) { float2 v = q[jj]; wp[NI / 2 + jj] = pack2(v.x, v.y); }
    }
    const float bias = b_ih[g] + b_hh[g];
    const float* xrow = x + (size_t)b * NT * NI;
    const int lane1 = g - 64;
    float2 xpre = make_float2(0.f, 0.f);
    if (g >= 64 && g < 128) {
        float2 v = ((const float2*)xrow)[lane1];
        zs[lane1] = pack2(v.x, v.y);
        xpre = ((const float2*)(xrow + NI))[lane1];
    }
    if (g < NH / 2) zs[NI / 2 + g] = 0u;
    float c = 0.f;
    const uint4* zs4 = (const uint4*)zs;
    for (int t = 0; t < NT; ++t) {
        block_sync_lds();
        float a0 = bias, a1 = 0.f, a2 = 0.f, a3 = 0.f;
        #pragma unroll
        for (int k = 0; k < 24; ++k) {
            uint4 zv = zs4[k];
            a0 = dot2(wp[4 * k + 0], zv.x, a0);
            a1 = dot2(wp[4 * k + 1], zv.y, a1);
            a2 = dot2(wp[4 * k + 2], zv.z, a2);
            a3 = dot2(wp[4 * k + 3], zv.w, a3);
        }
        float pre = (a0 + a1) + (a2 + a3);
        float av = (g >= 2 * NH && g < 3 * NH) ? fast_tanh(pre) : fast_sigmoid(pre);
        acts[g] = av;
        block_sync_lds();
        if (g < NH) {
            float i_t = acts[g];
            float f_t = acts[NH + g];
            float g_t = acts[2 * NH + g];
            float o_t = acts[3 * NH + g];
            c = fmaf(f_t, c, i_t * g_t);
            float hv = o_t * fast_tanh(c);
            float hn = __shfl_down(hv, 1);
            if ((g & 1) == 0) zs[NI / 2 + (g >> 1)] = pack2(hv, hn);
        } else if (g < 128) {
            if (t + 1 < NT) zs[lane1] = pack2(xpre.x, xpre.y);
            if (t + 2 < NT) xpre = ((const float2*)(xrow + (size_t)(t + 2) * NI))[lane1];
        }
    }
    block_sync_lds();
    if (g < NC) {
        float acc = b_cls[g];
        const float* wc = W_cls + g * NH;
        #pragma unroll
        for (int jj = 0; jj < NH / 2; ++jj) {
            half2v hp = __builtin_bit_cast(half2v, zs[NI / 2 + jj]);
            acc = fmaf(wc[2 * jj],     (float)hp[0], acc);
            acc = fmaf(wc[2 * jj + 1], (float)hp[1], acc);
        }
        out[b * NC + g] = acc;
    }
}

extern "C" void kernel_launch(void* const* d_in, const int* in_sizes, int n_in,
                              void* d_out, int out_size, void* d_ws, size_t ws_size,
                              hipStream_t stream) {
    const float* x     = (const float*)d_in[0];
    const float* W_ih  = (const float*)d_in[1];
    const float* W_hh  = (const float*)d_in[2];
    const float* b_ih  = (const float*)d_in[3];
    const float* b_hh  = (const float*)d_in[4];
    const float* W_cls = (const float*)d_in[5];
    const float* b_cls = (const float*)d_in[6];
    float* out = (float*)d_out;

    const size_t need = (size_t)NB * NT * 128 * sizeof(unsigned);   // 134 MB
    if (ws_size >= need) {
        unsigned* xp = (unsigned*)d_ws;
        lstm_xproj_kernel<<<(NB * NT) / 64, 256, 0, stream>>>(x, W_ih, xp);
        lstm_rec_kernel<<<NB, 64, 0, stream>>>(xp, W_hh, b_ih, b_hh, W_cls, b_cls, out);
    } else {
        lstm_fused_f16_kernel<<<NB, NG, 0, stream>>>(x, W_ih, W_hh, b_ih, b_hh,
                                                     W_cls, b_cls, out);
    }
}